// Round 10
// baseline (996.953 us; speedup 1.0000x reference)
//
#include <hip/hip_runtime.h>
#include <hip/hip_bf16.h>
#include <math.h>

#define DIMC 256
#define INNERC 128
#define HEADSC 4
#define DHC 32
#define QKVC 384

typedef __attribute__((ext_vector_type(8))) short bf16frag;   // 8 bf16 = 4 VGPRs
typedef __attribute__((ext_vector_type(4))) float f32x4;

__device__ __forceinline__ float gelu_exact(float x) {
    return 0.5f * x * (1.0f + erff(x * 0.70710678118654752f));
}

__device__ __forceinline__ float b2f(short s) {
    return __uint_as_float(((unsigned)(unsigned short)s) << 16);
}

__device__ __forceinline__ void gload_lds16(const void* g, void* l) {
    __builtin_amdgcn_global_load_lds(
        (const __attribute__((address_space(1))) void*)g,
        (__attribute__((address_space(3))) void*)l, 16, 0, 0);
}

// ---------------- LayerNorm: fp32 in, bf16 out ----------------
__global__ __launch_bounds__(256)
void ln_kernel(const float* __restrict__ x, const float* __restrict__ g,
               const float* __restrict__ b, __hip_bfloat16* __restrict__ out)
{
    int i = blockIdx.x;
    int t = threadIdx.x;
    float v = x[(size_t)i * DIMC + t];
    __shared__ float red[4];
    float s = v;
#pragma unroll
    for (int off = 32; off; off >>= 1) s += __shfl_xor(s, off);
    if ((t & 63) == 0) red[t >> 6] = s;
    __syncthreads();
    float mean = (red[0] + red[1] + red[2] + red[3]) * (1.f / DIMC);
    float c = v - mean;
    float s2 = c * c;
#pragma unroll
    for (int off = 32; off; off >>= 1) s2 += __shfl_xor(s2, off);
    __syncthreads();
    if ((t & 63) == 0) red[t >> 6] = s2;
    __syncthreads();
    float var = (red[0] + red[1] + red[2] + red[3]) * (1.f / DIMC);
    out[(size_t)i * DIMC + t] =
        __float2bfloat16(c * rsqrtf(var + 1e-5f) * g[t] + b[t]);
}

// ---------------- fp32 -> bf16 convert (n % 4 == 0) ----------------
__global__ void f2b_kernel(const float* __restrict__ src,
                           __hip_bfloat16* __restrict__ dst, int n)
{
    int i = (blockIdx.x * blockDim.x + threadIdx.x) * 4;
    if (i < n) {
        float4 v = *(const float4*)(src + i);
        dst[i + 0] = __float2bfloat16(v.x);
        dst[i + 1] = __float2bfloat16(v.y);
        dst[i + 2] = __float2bfloat16(v.z);
        dst[i + 3] = __float2bfloat16(v.w);
    }
}

// ---------------- pack wq/wk/wv -> wqkv bf16 [4][384][256], biases [4][384] ----
__global__ __launch_bounds__(256)
void packqkv_kernel(const float* __restrict__ wq, const float* __restrict__ wk,
                    const float* __restrict__ wv, const float* __restrict__ bq,
                    const float* __restrict__ bk, const float* __restrict__ bv,
                    __hip_bfloat16* __restrict__ wqkv, float* __restrict__ bqkv)
{
    int row = blockIdx.x;                 // 0 .. 4*384-1
    int l = row / QKVC, c = row % QKVC;
    int which = c >> 7, cc = c & 127;
    const float* srcw = which == 0 ? wq : which == 1 ? wk : wv;
    const float* srcb = which == 0 ? bq : which == 1 ? bk : bv;
    srcw += ((size_t)l * INNERC + cc) * DIMC;
    wqkv[(size_t)row * DIMC + threadIdx.x] = __float2bfloat16(srcw[threadIdx.x]);
    if (threadIdx.x == 0) bqkv[row] = srcb[l * INNERC + cc];
}

// ---------------- Streaming GEMM (K<=256): W-stationary, M-streaming --------
// C[M][OUT] = A[M][K] @ W[OUT][K]^T + bias.
// Block = (n-tile 64 cols, M-strip of `sublen` 64-row subtiles). 256 thr,
// 4 waves 2x2; wave tile 32x32 per subtile (2x2 16x16x32 frags, 16 AGPR).
// W[64][K] staged in LDS ONCE (swizzled); A-frags global->VGPR ping-pong
// (chunk = 4 K-slices); per-subtile epilogue. NO barriers in main loop.
// EPI: 0 = bias -> bf16; 1 = bias+gelu -> bf16; 2 = bias+res -> fp32.
template<int EPI, int K>
__global__ __launch_bounds__(256)
void stream_gemm(const __hip_bfloat16* __restrict__ A,
                 const __hip_bfloat16* __restrict__ W,
                 const float* __restrict__ bias, const float* __restrict__ res,
                 void* __restrict__ Cout, int M, int OUT,
                 int ntiles, int mstrips, int sublen)
{
    constexpr int RB = K * 2;              // row bytes
    constexpr int RCH = RB / 16;           // 16B chunks per row (16 or 32)
    __shared__ char wlds[64 * RB];

    int nwg = ntiles * mstrips;
    int orig = blockIdx.x;
    int q8 = nwg >> 3, r8 = nwg & 7;
    int xcd = orig & 7, loc = orig >> 3;
    int wgid = (xcd < r8 ? xcd * (q8 + 1) : r8 * (q8 + 1) + (xcd - r8) * q8) + loc;
    int strip = wgid / ntiles, nt = wgid % ntiles;

    int tid = threadIdx.x, lane = tid & 63;
    int w = tid >> 6, wr = w >> 1, wc = w & 1;
    int l15 = lane & 15, l4 = lane >> 4;

    // ---- stage W tile [64][K] once (source-swizzled so reads are 2-way max)
#pragma unroll
    for (int it = 0; it < (64 * RCH) / 256; ++it) {
        int c = it * 256 + tid;
        int r = c / RCH, cc = c % RCH;
        int sc = cc ^ (r & 15);
        gload_lds16((const char*)W + (size_t)(nt * 64 + r) * RB + sc * 16,
                    wlds + c * 16);
    }
    __syncthreads();                       // the only barrier

    int msubs = (M + 63) >> 6;
    int sub0 = strip * sublen;
    int sub1 = min(sub0 + sublen, msubs);
    const char* Ab = (const char*)A;

    f32x4 acc[2][2] = {};

    auto ldA = [&](int sub, int h, bf16frag (&dst)[2][4]) {
#pragma unroll
        for (int mf = 0; mf < 2; ++mf) {
            int row = sub * 64 + wr * 32 + mf * 16 + l15;
            row = min(row, M - 1);
            const char* rp = Ab + (size_t)row * RB + h * 256 + l4 * 16;
#pragma unroll
            for (int s = 0; s < 4; ++s)
                dst[mf][s] = *(const bf16frag*)(rp + s * 64);
        }
    };

    auto cmp = [&](int h, bf16frag (&src)[2][4]) {
#pragma unroll
        for (int s = 0; s < 4; ++s) {
            int ch = (h * 4 + s) * 4 + l4;
            bf16frag bfr[2];
#pragma unroll
            for (int nf = 0; nf < 2; ++nf) {
                int br = wc * 32 + nf * 16 + l15;
                bfr[nf] = *(const bf16frag*)(wlds + br * RB + ((ch ^ (br & 15)) << 4));
            }
#pragma unroll
            for (int mf = 0; mf < 2; ++mf)
#pragma unroll
                for (int nf = 0; nf < 2; ++nf)
                    acc[mf][nf] = __builtin_amdgcn_mfma_f32_16x16x32_bf16(
                        src[mf][s], bfr[nf], acc[mf][nf], 0, 0, 0);
        }
    };

    auto epi = [&](int sub) {
#pragma unroll
        for (int mf = 0; mf < 2; ++mf)
#pragma unroll
            for (int rr = 0; rr < 4; ++rr) {
                int grow = sub * 64 + wr * 32 + mf * 16 + l4 * 4 + rr;
                if (grow < M) {
#pragma unroll
                    for (int nf = 0; nf < 2; ++nf) {
                        int gcol = nt * 64 + wc * 32 + nf * 16 + l15;
                        float val = acc[mf][nf][rr] + bias[gcol];
                        if (EPI == 1) val = gelu_exact(val);
                        if (EPI == 2) {
                            val += res[(size_t)grow * OUT + gcol];
                            ((float*)Cout)[(size_t)grow * OUT + gcol] = val;
                        } else {
                            ((__hip_bfloat16*)Cout)[(size_t)grow * OUT + gcol] =
                                __float2bfloat16(val);
                        }
                    }
                }
            }
#pragma unroll
        for (int mf = 0; mf < 2; ++mf)
#pragma unroll
            for (int nf = 0; nf < 2; ++nf)
                acc[mf][nf] = f32x4{0.f, 0.f, 0.f, 0.f};
    };

    bf16frag pA[2][4], pB[2][4];
    if constexpr (K == 256) {
        ldA(sub0, 0, pA);
        for (int sub = sub0; sub < sub1; ++sub) {
            ldA(sub, 1, pB);               // issue h1 loads
            cmp(0, pA);                    // compute h0
            if (sub + 1 < sub1) ldA(sub + 1, 0, pA);   // issue next-sub h0
            cmp(1, pB);                    // compute h1
            epi(sub);
        }
    } else {                               // K == 128: one chunk per subtile
        int sub = sub0;
        ldA(sub, 0, pA);
        for (; sub + 1 < sub1; sub += 2) {
            ldA(sub + 1, 0, pB);
            cmp(0, pA); epi(sub);
            if (sub + 2 < sub1) ldA(sub + 2, 0, pA);
            cmp(0, pB); epi(sub + 1);
        }
        if (sub < sub1) { cmp(0, pA); epi(sub); }
    }
}

// ---------------- MFMA GEMM v3 (kept for FF2, K=1024): 2-phase dbuf BN=64 ---
template<int EPI>
__global__ __launch_bounds__(256)
void mfma_gemm(const __hip_bfloat16* __restrict__ A,
               const __hip_bfloat16* __restrict__ W,
               const float* __restrict__ bias, const float* __restrict__ res,
               void* __restrict__ Cout, int M, int K, int OUT,
               int mtiles, int ntiles)
{
    constexpr int ASZ = 128 * 128;
    constexpr int WSZ = 64 * 128;
    __shared__ char lds[2 * ASZ + 2 * WSZ];

    int nwg = mtiles * ntiles;
    int orig = blockIdx.x;
    int q = nwg >> 3, r = nwg & 7;
    int xcd = orig & 7, loc = orig >> 3;
    int wgid = (xcd < r ? xcd * (q + 1) : r * (q + 1) + (xcd - r) * q) + loc;
    int bm = (wgid / ntiles) * 128;
    int bn = (wgid % ntiles) * 64;

    int tid = threadIdx.x;
    int lane = tid & 63;
    int w = tid >> 6;
    int wr = w >> 1, wc = w & 1;

    f32x4 acc[4][2] = {};

    auto stage = [&](int t, int b) {
        int k0 = t * 64;
        char* Asb = lds + b * ASZ;
        char* Wsb = lds + 2 * ASZ + b * WSZ;
#pragma unroll
        for (int it = 0; it < 4; ++it) {
            int chunk = it * 256 + tid;
            int rr = chunk >> 3;
            int sc = (chunk & 7) ^ (rr & 7);
            int grow = bm + rr;
            if (grow < M)
                gload_lds16((const char*)A + ((size_t)grow * K + k0) * 2 + sc * 16,
                            Asb + chunk * 16);
        }
#pragma unroll
        for (int it = 0; it < 2; ++it) {
            int chunk = it * 256 + tid;
            int rr = chunk >> 3;
            int sc = (chunk & 7) ^ (rr & 7);
            gload_lds16((const char*)W + ((size_t)(bn + rr) * K + k0) * 2 + sc * 16,
                        Wsb + chunk * 16);
        }
    };

    int nk = K >> 6;
    stage(0, 0);
    __syncthreads();
    for (int t = 0; t < nk; ++t) {
        int cur = t & 1;
        if (t + 1 < nk) stage(t + 1, cur ^ 1);
        char* As = lds + cur * ASZ;
        char* Ws = lds + 2 * ASZ + cur * WSZ;
#pragma unroll
        for (int s = 0; s < 2; ++s) {
            bf16frag af[4], bfr[2];
            int kb = s * 64 + ((lane >> 4) << 4);
#pragma unroll
            for (int m = 0; m < 4; ++m) {
                int ar = wr * 64 + m * 16 + (lane & 15);
                af[m] = *(const bf16frag*)(As + ar * 128 + (kb ^ ((ar & 7) << 4)));
            }
#pragma unroll
            for (int n = 0; n < 2; ++n) {
                int br = wc * 32 + n * 16 + (lane & 15);
                bfr[n] = *(const bf16frag*)(Ws + br * 128 + (kb ^ ((br & 7) << 4)));
            }
#pragma unroll
            for (int m = 0; m < 4; ++m)
#pragma unroll
                for (int n = 0; n < 2; ++n)
                    acc[m][n] = __builtin_amdgcn_mfma_f32_16x16x32_bf16(
                        af[m], bfr[n], acc[m][n], 0, 0, 0);
        }
        __syncthreads();
    }

#pragma unroll
    for (int m = 0; m < 4; ++m)
#pragma unroll
        for (int rr = 0; rr < 4; ++rr) {
            int grow = bm + wr * 64 + m * 16 + ((lane >> 4) << 2) + rr;
            if (grow < M) {
#pragma unroll
                for (int n = 0; n < 2; ++n) {
                    int gcol = bn + wc * 32 + n * 16 + (lane & 15);
                    float val = acc[m][n][rr] + bias[gcol];
                    if (EPI == 1) val = gelu_exact(val);
                    if (EPI == 2) {
                        val += res[(size_t)grow * OUT + gcol];
                        ((float*)Cout)[(size_t)grow * OUT + gcol] = val;
                    } else {
                        ((__hip_bfloat16*)Cout)[(size_t)grow * OUT + gcol] =
                            __float2bfloat16(val);
                    }
                }
            }
        }
}

// ---------------- CSR build ----------------
__global__ void count_kernel(const int* __restrict__ dst, int* __restrict__ count, int E)
{
    int e = blockIdx.x * blockDim.x + threadIdx.x;
    if (e < E) atomicAdd(&count[dst[e]], 1);
}

__global__ __launch_bounds__(1024)
void scan_kernel(const int* __restrict__ count, int* __restrict__ rowptr, int N)
{
    __shared__ int sdata[1024];
    __shared__ int carry_s;
    int t = threadIdx.x;
    if (t == 0) { carry_s = 0; rowptr[0] = 0; }
    __syncthreads();
    for (int base = 0; base < N; base += 1024) {
        int idx = base + t;
        int v = (idx < N) ? count[idx] : 0;
        sdata[t] = v;
        __syncthreads();
        for (int off = 1; off < 1024; off <<= 1) {
            int add = (t >= off) ? sdata[t - off] : 0;
            __syncthreads();
            sdata[t] += add;
            __syncthreads();
        }
        if (idx < N) rowptr[idx + 1] = carry_s + sdata[t];
        __syncthreads();
        if (t == 0) carry_s += sdata[1023];
        __syncthreads();
    }
}

__global__ void scatter_kernel(const int* __restrict__ src, const int* __restrict__ dst,
                               const int* __restrict__ rowptr, int* __restrict__ cursor,
                               int* __restrict__ srcperm, int E)
{
    int e = blockIdx.x * blockDim.x + threadIdx.x;
    if (e < E) {
        int d = dst[e];
        int pos = rowptr[d] + atomicAdd(&cursor[d], 1);
        srcperm[pos] = src[e];
    }
}

// ---------------- Attention: one WAVE per node, ILP-restructured ------------
__global__ __launch_bounds__(256)
void attn_kernel(const __hip_bfloat16* __restrict__ qkv, const int* __restrict__ rowptr,
                 const int* __restrict__ srcperm, __hip_bfloat16* __restrict__ agg,
                 int N)
{
    int wid = (blockIdx.x * 256 + threadIdx.x) >> 6;   // node index
    if (wid >= N) return;
    int lane = threadIdx.x & 63;
    int h = lane >> 4, u = lane & 15;
    int i = wid;
    int beg = rowptr[i], deg = rowptr[i + 1] - beg;
    const short* base = (const short*)qkv;
    const float scale = 0.17677669529663687f; // 1/sqrt(32)

    bf16frag qf[4];
    const short* qr = base + (size_t)i * QKVC + h * 32;
#pragma unroll
    for (int c = 0; c < 4; ++c) qf[c] = *(const bf16frag*)(qr + c * 8);

    float m_run = -3.4e38f, d_run = 0.f;
    float accx = 0.f, accy = 0.f;

    int j = (u < deg) ? srcperm[beg + u] : i;

    for (int c0 = 0; c0 < deg; c0 += 16) {
        int cn = min(16, deg - c0);
        bool valid = (u < cn);

        const short* kr = base + (size_t)j * QKVC + 128 + h * 32;
        bf16frag kf[4];
#pragma unroll
        for (int c = 0; c < 4; ++c) kf[c] = *(const bf16frag*)(kr + c * 8);

        int nxt = c0 + 16 + u;
        int jn = (nxt < deg) ? srcperm[beg + nxt] : i;

        float dot = 0.f;
#pragma unroll
        for (int c = 0; c < 4; ++c)
#pragma unroll
            for (int e = 0; e < 8; ++e)
                dot += b2f(qf[c][e]) * b2f(kf[c][e]);
        float alpha = valid ? dot * scale : -3.4e38f;

        float cm = alpha;
#pragma unroll
        for (int off = 8; off; off >>= 1) cm = fmaxf(cm, __shfl_xor(cm, off));
        float m_new = fmaxf(m_run, cm);
        float rescale = expf(m_run - m_new);
        float w = valid ? expf(alpha - m_new) : 0.f;
        float dsum = w;
#pragma unroll
        for (int off = 8; off; off >>= 1) dsum += __shfl_xor(dsum, off);
        d_run = d_run * rescale + dsum;
        m_run = m_new;
        accx *= rescale;
        accy *= rescale;

        float wes[16];
        unsigned vws[16];
#pragma unroll
        for (int e = 0; e < 16; ++e) {
            wes[e] = __shfl(w, h * 16 + e);
            int je = __shfl(j, h * 16 + e);        // invalid slots -> row i
            vws[e] = *(const unsigned*)(base + (size_t)je * QKVC + 256 + h * 32 + u * 2);
        }
#pragma unroll
        for (int e = 0; e < 16; ++e) {
            accx += wes[e] * b2f((short)(vws[e] & 0xffff));
            accy += wes[e] * b2f((short)(vws[e] >> 16));
        }
        j = jn;
    }

    float inv = 1.f / (d_run + 1e-16f);
    __hip_bfloat16* outp = agg + (size_t)i * INNERC + h * 32 + u * 2;
    outp[0] = __float2bfloat16(accx * inv);
    outp[1] = __float2bfloat16(accy * inv);
}

// ---------------- Launch ----------------
extern "C" void kernel_launch(void* const* d_in, const int* in_sizes, int n_in,
                              void* d_out, int out_size, void* d_ws, size_t ws_size,
                              hipStream_t stream)
{
    const float* x    = (const float*)d_in[0];
    const int*   ei   = (const int*)  d_in[1];
    const float* ln1g = (const float*)d_in[2];
    const float* ln1b = (const float*)d_in[3];
    const float* wq   = (const float*)d_in[4];
    const float* bq   = (const float*)d_in[5];
    const float* wk   = (const float*)d_in[6];
    const float* bk   = (const float*)d_in[7];
    const float* wv   = (const float*)d_in[8];
    const float* bv   = (const float*)d_in[9];
    const float* wo   = (const float*)d_in[10];
    const float* bo   = (const float*)d_in[11];
    const float* ln2g = (const float*)d_in[12];
    const float* ln2b = (const float*)d_in[13];
    const float* w1   = (const float*)d_in[14];
    const float* b1   = (const float*)d_in[15];
    const float* w2   = (const float*)d_in[16];
    const float* b2   = (const float*)d_in[17];

    const int N = in_sizes[0] / DIMC;   // 20000
    const int E = in_sizes[1] / 2;      // 320000
    const int* srcIdx = ei;
    const int* dstIdx = ei + E;

    char* p = (char*)d_ws;
    auto alloc = [&](size_t bytes) {
        char* r = p;
        p += (bytes + 255) & ~(size_t)255;
        return r;
    };
    float*          xbuf   = (float*)alloc((size_t)N * DIMC * 4);
    __hip_bfloat16* h      = (__hip_bfloat16*)alloc((size_t)N * DIMC * 2);
    __hip_bfloat16* qkv    = (__hip_bfloat16*)alloc((size_t)N * QKVC * 2);
    __hip_bfloat16* agg    = (__hip_bfloat16*)alloc((size_t)N * INNERC * 2);
    __hip_bfloat16* u      = (__hip_bfloat16*)alloc((size_t)N * 1024 * 2);
    int*            rowptr = (int*)alloc((size_t)(N + 1) * 4);
    int*            cnt    = (int*)alloc((size_t)N * 4);
    int*            srcperm= (int*)alloc((size_t)E * 4);
    __hip_bfloat16* wqkvB  = (__hip_bfloat16*)alloc((size_t)4 * QKVC * DIMC * 2);
    float*          bqkvF  = (float*)alloc((size_t)4 * QKVC * 4);
    __hip_bfloat16* woB    = (__hip_bfloat16*)alloc((size_t)4 * DIMC * INNERC * 2);
    __hip_bfloat16* w1B    = (__hip_bfloat16*)alloc((size_t)4 * 1024 * DIMC * 2);
    __hip_bfloat16* w2B    = (__hip_bfloat16*)alloc((size_t)4 * DIMC * 1024 * 2);

    // Weight conversion (per-call, deterministic)
    packqkv_kernel<<<4 * QKVC, 256, 0, stream>>>(wq, wk, wv, bq, bk, bv, wqkvB, bqkvF);
    {
        int n = 4 * DIMC * INNERC;
        f2b_kernel<<<(n / 4 + 255) / 256, 256, 0, stream>>>(wo, woB, n);
        n = 4 * 1024 * DIMC;
        f2b_kernel<<<(n / 4 + 255) / 256, 256, 0, stream>>>(w1, w1B, n);
        f2b_kernel<<<(n / 4 + 255) / 256, 256, 0, stream>>>(w2, w2B, n);
    }

    // CSR build
    hipMemsetAsync(cnt, 0, (size_t)N * 4, stream);
    count_kernel<<<(E + 255) / 256, 256, 0, stream>>>(dstIdx, cnt, E);
    scan_kernel<<<1, 1024, 0, stream>>>(cnt, rowptr, N);
    hipMemsetAsync(cnt, 0, (size_t)N * 4, stream);
    scatter_kernel<<<(E + 255) / 256, 256, 0, stream>>>(srcIdx, dstIdx, rowptr, cnt, srcperm, E);

    int mt = (N + 127) / 128;        // 157 (for FF2 kernel)
    int attnBlocks = (N * 64 + 255) / 256;
    for (int l = 0; l < 4; ++l) {
        const float* xin = (l == 0) ? x : xbuf;
        ln_kernel<<<N, 256, 0, stream>>>(xin, ln1g + l * DIMC, ln1b + l * DIMC, h);
        // QKV: OUT=384, K=256: 6 ntiles x 63 strips (sublen 5) = 378 blocks
        stream_gemm<0, 256><<<6 * 63, 256, 0, stream>>>(
            h, wqkvB + (size_t)l * QKVC * DIMC, bqkvF + l * QKVC, nullptr,
            qkv, N, QKVC, 6, 63, 5);
        attn_kernel<<<attnBlocks, 256, 0, stream>>>(qkv, rowptr, srcperm, agg, N);
        // out-proj: OUT=256, K=128: 4 ntiles x 79 strips (sublen 4) = 316 blocks
        stream_gemm<2, 128><<<4 * 79, 256, 0, stream>>>(
            agg, woB + (size_t)l * DIMC * INNERC, bo + l * DIMC, xin,
            xbuf, N, DIMC, 4, 79, 4);
        ln_kernel<<<N, 256, 0, stream>>>(xbuf, ln2g + l * DIMC, ln2b + l * DIMC, h);
        // FF1: OUT=1024, K=256: 16 ntiles x 20 strips (sublen 16) = 320 blocks
        stream_gemm<1, 256><<<16 * 20, 256, 0, stream>>>(
            h, w1B + (size_t)l * 1024 * DIMC, b1 + l * 1024, nullptr,
            u, N, 1024, 16, 20, 16);
        float* xout = (l == 3) ? (float*)d_out : xbuf;
        // FF2: OUT=256, K=1024 -> keep v3 (deep K-loop), 628 blocks
        mfma_gemm<2><<<mt * 4, 256, 0, stream>>>(
            u, w2B + (size_t)l * DIMC * 1024, b2 + l * DIMC, xbuf,
            xout, N, 1024, DIMC, mt, 4);
    }
}

// Round 11
// 605.932 us; speedup vs baseline: 1.6453x; 1.6453x over previous
//
#include <hip/hip_runtime.h>
#include <hip/hip_bf16.h>
#include <math.h>

#define DIMC 256
#define INNERC 128
#define HEADSC 4
#define DHC 32
#define QKVC 384

typedef __attribute__((ext_vector_type(8))) short bf16frag;   // 8 bf16 = 4 VGPRs
typedef __attribute__((ext_vector_type(4))) float f32x4;

__device__ __forceinline__ float gelu_exact(float x) {
    return 0.5f * x * (1.0f + erff(x * 0.70710678118654752f));
}

__device__ __forceinline__ float b2f(short s) {
    return __uint_as_float(((unsigned)(unsigned short)s) << 16);
}

__device__ __forceinline__ void gload_lds16(const void* g, void* l) {
    __builtin_amdgcn_global_load_lds(
        (const __attribute__((address_space(1))) void*)g,
        (__attribute__((address_space(3))) void*)l, 16, 0, 0);
}

// ---------------- LayerNorm: one WAVE per row, no barriers ----------------
__global__ __launch_bounds__(256)
void ln_kernel(const float* __restrict__ x, const float* __restrict__ g,
               const float* __restrict__ b, __hip_bfloat16* __restrict__ out,
               int N)
{
    int row = blockIdx.x * 4 + (threadIdx.x >> 6);
    if (row >= N) return;
    int lane = threadIdx.x & 63;
    float4 v = *(const float4*)(x + (size_t)row * DIMC + lane * 4);
    float s = v.x + v.y + v.z + v.w;
    float s2 = v.x * v.x + v.y * v.y + v.z * v.z + v.w * v.w;
#pragma unroll
    for (int off = 32; off; off >>= 1) {
        s += __shfl_xor(s, off);
        s2 += __shfl_xor(s2, off);
    }
    float mean = s * (1.f / DIMC);
    float var = s2 * (1.f / DIMC) - mean * mean;
    float rs = rsqrtf(var + 1e-5f);
    float4 gv = *(const float4*)(g + lane * 4);
    float4 bv = *(const float4*)(b + lane * 4);
    __hip_bfloat16 o[4];
    o[0] = __float2bfloat16((v.x - mean) * rs * gv.x + bv.x);
    o[1] = __float2bfloat16((v.y - mean) * rs * gv.y + bv.y);
    o[2] = __float2bfloat16((v.z - mean) * rs * gv.z + bv.z);
    o[3] = __float2bfloat16((v.w - mean) * rs * gv.w + bv.w);
    *(short4*)(out + (size_t)row * DIMC + lane * 4) = *(short4*)o;
}

// ---------------- fp32 -> bf16 convert (n % 4 == 0) ----------------
__global__ void f2b_kernel(const float* __restrict__ src,
                           __hip_bfloat16* __restrict__ dst, int n)
{
    int i = (blockIdx.x * blockDim.x + threadIdx.x) * 4;
    if (i < n) {
        float4 v = *(const float4*)(src + i);
        dst[i + 0] = __float2bfloat16(v.x);
        dst[i + 1] = __float2bfloat16(v.y);
        dst[i + 2] = __float2bfloat16(v.z);
        dst[i + 3] = __float2bfloat16(v.w);
    }
}

// ---------------- pack wq/wk/wv -> wqkv bf16 [4][384][256], biases [4][384] ----
__global__ __launch_bounds__(256)
void packqkv_kernel(const float* __restrict__ wq, const float* __restrict__ wk,
                    const float* __restrict__ wv, const float* __restrict__ bq,
                    const float* __restrict__ bk, const float* __restrict__ bv,
                    __hip_bfloat16* __restrict__ wqkv, float* __restrict__ bqkv)
{
    int row = blockIdx.x;                 // 0 .. 4*384-1
    int l = row / QKVC, c = row % QKVC;
    int which = c >> 7, cc = c & 127;
    const float* srcw = which == 0 ? wq : which == 1 ? wk : wv;
    const float* srcb = which == 0 ? bq : which == 1 ? bk : bv;
    srcw += ((size_t)l * INNERC + cc) * DIMC;
    wqkv[(size_t)row * DIMC + threadIdx.x] = __float2bfloat16(srcw[threadIdx.x]);
    if (threadIdx.x == 0) bqkv[row] = srcb[l * INNERC + cc];
}

// ---------------- MFMA GEMM v4: dbuf + COUNTED vmcnt (T4), BN=64 ------------
// C[M][OUT] = A[M][K] @ W[OUT][K]^T + bias.  BM=128, BK=64, BN=64.
// Key vs v3: raw s_barrier + s_waitcnt vmcnt(6) instead of __syncthreads'
// vmcnt(0) drain -> the prefetched next-tile loads stay in flight across the
// barrier (m218 mechanism). Staging is UNCONDITIONAL (row clamped to M-1) so
// every wave's outstanding-load count is exactly 6 per stage.
// EPI: 0 = bias -> bf16; 1 = bias+gelu -> bf16; 2 = bias+res -> fp32.
template<int EPI>
__global__ __launch_bounds__(256)
void mfma_gemm(const __hip_bfloat16* __restrict__ A,
               const __hip_bfloat16* __restrict__ W,
               const float* __restrict__ bias, const float* __restrict__ res,
               void* __restrict__ Cout, int M, int K, int OUT,
               int mtiles, int ntiles)
{
    constexpr int ASZ = 128 * 128;          // one A buf (16KB)
    constexpr int WSZ = 64 * 128;           // one W buf (8KB)
    __shared__ char lds[2 * ASZ + 2 * WSZ];

    int nwg = mtiles * ntiles;
    int orig = blockIdx.x;
    int q = nwg >> 3, r = nwg & 7;
    int xcd = orig & 7, loc = orig >> 3;
    int wgid = (xcd < r ? xcd * (q + 1) : r * (q + 1) + (xcd - r) * q) + loc;
    int bm = (wgid / ntiles) * 128;
    int bn = (wgid % ntiles) * 64;

    int tid = threadIdx.x;
    int lane = tid & 63;
    int w = tid >> 6;
    int wr = w >> 1, wc = w & 1;

    f32x4 acc[4][2] = {};

    auto stage = [&](int t, int b) {
        int k0 = t * 64;
        char* Asb = lds + b * ASZ;
        char* Wsb = lds + 2 * ASZ + b * WSZ;
#pragma unroll
        for (int it = 0; it < 4; ++it) {             // A: 4 loads/thread
            int chunk = it * 256 + tid;
            int rr = chunk >> 3;
            int sc = (chunk & 7) ^ (rr & 7);
            int grow = min(bm + rr, M - 1);          // clamp: ALWAYS issue
            gload_lds16((const char*)A + ((size_t)grow * K + k0) * 2 + sc * 16,
                        Asb + chunk * 16);
        }
#pragma unroll
        for (int it = 0; it < 2; ++it) {             // W: 2 loads/thread
            int chunk = it * 256 + tid;
            int rr = chunk >> 3;
            int sc = (chunk & 7) ^ (rr & 7);
            gload_lds16((const char*)W + ((size_t)(bn + rr) * K + k0) * 2 + sc * 16,
                        Wsb + chunk * 16);
        }
    };

    int nk = K >> 6;
    stage(0, 0);
    for (int t = 0; t < nk; ++t) {
        int cur = t & 1;
        if (t + 1 < nk) {
            stage(t + 1, cur ^ 1);                   // prefetch into other buf
            asm volatile("s_waitcnt vmcnt(6)" ::: "memory");   // wait tile t only
        } else {
            asm volatile("s_waitcnt vmcnt(0)" ::: "memory");
        }
        __builtin_amdgcn_s_barrier();                // tile t visible, no drain
        char* As = lds + cur * ASZ;
        char* Ws = lds + 2 * ASZ + cur * WSZ;
#pragma unroll
        for (int s = 0; s < 2; ++s) {
            bf16frag af[4], bfr[2];
            int kb = s * 64 + ((lane >> 4) << 4);
#pragma unroll
            for (int m = 0; m < 4; ++m) {
                int ar = wr * 64 + m * 16 + (lane & 15);
                af[m] = *(const bf16frag*)(As + ar * 128 + (kb ^ ((ar & 7) << 4)));
            }
#pragma unroll
            for (int n = 0; n < 2; ++n) {
                int br = wc * 32 + n * 16 + (lane & 15);
                bfr[n] = *(const bf16frag*)(Ws + br * 128 + (kb ^ ((br & 7) << 4)));
            }
#pragma unroll
            for (int m = 0; m < 4; ++m)
#pragma unroll
                for (int n = 0; n < 2; ++n)
                    acc[m][n] = __builtin_amdgcn_mfma_f32_16x16x32_bf16(
                        af[m], bfr[n], acc[m][n], 0, 0, 0);
        }
        __builtin_amdgcn_s_barrier();                // all reads of buf done (WAR)
    }

#pragma unroll
    for (int m = 0; m < 4; ++m)
#pragma unroll
        for (int rr = 0; rr < 4; ++rr) {
            int grow = bm + wr * 64 + m * 16 + ((lane >> 4) << 2) + rr;
            if (grow < M) {
#pragma unroll
                for (int n = 0; n < 2; ++n) {
                    int gcol = bn + wc * 32 + n * 16 + (lane & 15);
                    float val = acc[m][n][rr] + bias[gcol];
                    if (EPI == 1) val = gelu_exact(val);
                    if (EPI == 2) {
                        val += res[(size_t)grow * OUT + gcol];
                        ((float*)Cout)[(size_t)grow * OUT + gcol] = val;
                    } else {
                        ((__hip_bfloat16*)Cout)[(size_t)grow * OUT + gcol] =
                            __float2bfloat16(val);
                    }
                }
            }
        }
}

// ---------------- CSR build ----------------
__global__ void count_kernel(const int* __restrict__ dst, int* __restrict__ count, int E)
{
    int e = blockIdx.x * blockDim.x + threadIdx.x;
    if (e < E) atomicAdd(&count[dst[e]], 1);
}

__global__ __launch_bounds__(1024)
void scan_kernel(const int* __restrict__ count, int* __restrict__ rowptr, int N)
{
    __shared__ int sdata[1024];
    __shared__ int carry_s;
    int t = threadIdx.x;
    if (t == 0) { carry_s = 0; rowptr[0] = 0; }
    __syncthreads();
    for (int base = 0; base < N; base += 1024) {
        int idx = base + t;
        int v = (idx < N) ? count[idx] : 0;
        sdata[t] = v;
        __syncthreads();
        for (int off = 1; off < 1024; off <<= 1) {
            int add = (t >= off) ? sdata[t - off] : 0;
            __syncthreads();
            sdata[t] += add;
            __syncthreads();
        }
        if (idx < N) rowptr[idx + 1] = carry_s + sdata[t];
        __syncthreads();
        if (t == 0) carry_s += sdata[1023];
        __syncthreads();
    }
}

__global__ void scatter_kernel(const int* __restrict__ src, const int* __restrict__ dst,
                               const int* __restrict__ rowptr, int* __restrict__ cursor,
                               int* __restrict__ srcperm, int E)
{
    int e = blockIdx.x * blockDim.x + threadIdx.x;
    if (e < E) {
        int d = dst[e];
        int pos = rowptr[d] + atomicAdd(&cursor[d], 1);
        srcperm[pos] = src[e];
    }
}

// ---------------- Attention: one WAVE per node, ILP-restructured ------------
__global__ __launch_bounds__(256)
void attn_kernel(const __hip_bfloat16* __restrict__ qkv, const int* __restrict__ rowptr,
                 const int* __restrict__ srcperm, __hip_bfloat16* __restrict__ agg,
                 int N)
{
    int wid = (blockIdx.x * 256 + threadIdx.x) >> 6;   // node index
    if (wid >= N) return;
    int lane = threadIdx.x & 63;
    int h = lane >> 4, u = lane & 15;
    int i = wid;
    int beg = rowptr[i], deg = rowptr[i + 1] - beg;
    const short* base = (const short*)qkv;
    const float scale = 0.17677669529663687f; // 1/sqrt(32)

    bf16frag qf[4];
    const short* qr = base + (size_t)i * QKVC + h * 32;
#pragma unroll
    for (int c = 0; c < 4; ++c) qf[c] = *(const bf16frag*)(qr + c * 8);

    float m_run = -3.4e38f, d_run = 0.f;
    float accx = 0.f, accy = 0.f;

    int j = (u < deg) ? srcperm[beg + u] : i;

    for (int c0 = 0; c0 < deg; c0 += 16) {
        int cn = min(16, deg - c0);
        bool valid = (u < cn);

        const short* kr = base + (size_t)j * QKVC + 128 + h * 32;
        bf16frag kf[4];
#pragma unroll
        for (int c = 0; c < 4; ++c) kf[c] = *(const bf16frag*)(kr + c * 8);

        int nxt = c0 + 16 + u;
        int jn = (nxt < deg) ? srcperm[beg + nxt] : i;

        float dot = 0.f;
#pragma unroll
        for (int c = 0; c < 4; ++c)
#pragma unroll
            for (int e = 0; e < 8; ++e)
                dot += b2f(qf[c][e]) * b2f(kf[c][e]);
        float alpha = valid ? dot * scale : -3.4e38f;

        float cm = alpha;
#pragma unroll
        for (int off = 8; off; off >>= 1) cm = fmaxf(cm, __shfl_xor(cm, off));
        float m_new = fmaxf(m_run, cm);
        float rescale = expf(m_run - m_new);
        float w = valid ? expf(alpha - m_new) : 0.f;
        float dsum = w;
#pragma unroll
        for (int off = 8; off; off >>= 1) dsum += __shfl_xor(dsum, off);
        d_run = d_run * rescale + dsum;
        m_run = m_new;
        accx *= rescale;
        accy *= rescale;

        float wes[16];
        unsigned vws[16];
#pragma unroll
        for (int e = 0; e < 16; ++e) {
            wes[e] = __shfl(w, h * 16 + e);
            int je = __shfl(j, h * 16 + e);        // invalid slots -> row i
            vws[e] = *(const unsigned*)(base + (size_t)je * QKVC + 256 + h * 32 + u * 2);
        }
#pragma unroll
        for (int e = 0; e < 16; ++e) {
            accx += wes[e] * b2f((short)(vws[e] & 0xffff));
            accy += wes[e] * b2f((short)(vws[e] >> 16));
        }
        j = jn;
    }

    float inv = 1.f / (d_run + 1e-16f);
    __hip_bfloat16* outp = agg + (size_t)i * INNERC + h * 32 + u * 2;
    outp[0] = __float2bfloat16(accx * inv);
    outp[1] = __float2bfloat16(accy * inv);
}

// ---------------- Launch ----------------
extern "C" void kernel_launch(void* const* d_in, const int* in_sizes, int n_in,
                              void* d_out, int out_size, void* d_ws, size_t ws_size,
                              hipStream_t stream)
{
    const float* x    = (const float*)d_in[0];
    const int*   ei   = (const int*)  d_in[1];
    const float* ln1g = (const float*)d_in[2];
    const float* ln1b = (const float*)d_in[3];
    const float* wq   = (const float*)d_in[4];
    const float* bq   = (const float*)d_in[5];
    const float* wk   = (const float*)d_in[6];
    const float* bk   = (const float*)d_in[7];
    const float* wv   = (const float*)d_in[8];
    const float* bv   = (const float*)d_in[9];
    const float* wo   = (const float*)d_in[10];
    const float* bo   = (const float*)d_in[11];
    const float* ln2g = (const float*)d_in[12];
    const float* ln2b = (const float*)d_in[13];
    const float* w1   = (const float*)d_in[14];
    const float* b1   = (const float*)d_in[15];
    const float* w2   = (const float*)d_in[16];
    const float* b2   = (const float*)d_in[17];

    const int N = in_sizes[0] / DIMC;   // 20000
    const int E = in_sizes[1] / 2;      // 320000
    const int* srcIdx = ei;
    const int* dstIdx = ei + E;

    char* p = (char*)d_ws;
    auto alloc = [&](size_t bytes) {
        char* r = p;
        p += (bytes + 255) & ~(size_t)255;
        return r;
    };
    float*          xbuf   = (float*)alloc((size_t)N * DIMC * 4);
    __hip_bfloat16* h      = (__hip_bfloat16*)alloc((size_t)N * DIMC * 2);
    __hip_bfloat16* qkv    = (__hip_bfloat16*)alloc((size_t)N * QKVC * 2);
    __hip_bfloat16* agg    = (__hip_bfloat16*)alloc((size_t)N * INNERC * 2);
    __hip_bfloat16* u      = (__hip_bfloat16*)alloc((size_t)N * 1024 * 2);
    int*            rowptr = (int*)alloc((size_t)(N + 1) * 4);
    int*            cnt    = (int*)alloc((size_t)N * 4);
    int*            srcperm= (int*)alloc((size_t)E * 4);
    __hip_bfloat16* wqkvB  = (__hip_bfloat16*)alloc((size_t)4 * QKVC * DIMC * 2);
    float*          bqkvF  = (float*)alloc((size_t)4 * QKVC * 4);
    __hip_bfloat16* woB    = (__hip_bfloat16*)alloc((size_t)4 * DIMC * INNERC * 2);
    __hip_bfloat16* w1B    = (__hip_bfloat16*)alloc((size_t)4 * 1024 * DIMC * 2);
    __hip_bfloat16* w2B    = (__hip_bfloat16*)alloc((size_t)4 * DIMC * 1024 * 2);

    // Weight conversion (per-call, deterministic)
    packqkv_kernel<<<4 * QKVC, 256, 0, stream>>>(wq, wk, wv, bq, bk, bv, wqkvB, bqkvF);
    {
        int n = 4 * DIMC * INNERC;
        f2b_kernel<<<(n / 4 + 255) / 256, 256, 0, stream>>>(wo, woB, n);
        n = 4 * 1024 * DIMC;
        f2b_kernel<<<(n / 4 + 255) / 256, 256, 0, stream>>>(w1, w1B, n);
        f2b_kernel<<<(n / 4 + 255) / 256, 256, 0, stream>>>(w2, w2B, n);
    }

    // CSR build
    hipMemsetAsync(cnt, 0, (size_t)N * 4, stream);
    count_kernel<<<(E + 255) / 256, 256, 0, stream>>>(dstIdx, cnt, E);
    scan_kernel<<<1, 1024, 0, stream>>>(cnt, rowptr, N);
    hipMemsetAsync(cnt, 0, (size_t)N * 4, stream);
    scatter_kernel<<<(E + 255) / 256, 256, 0, stream>>>(srcIdx, dstIdx, rowptr, cnt, srcperm, E);

    int mt = (N + 127) / 128;        // 157
    int lnBlocks = (N + 3) / 4;      // 5000
    int attnBlocks = (N * 64 + 255) / 256;
    for (int l = 0; l < 4; ++l) {
        const float* xin = (l == 0) ? x : xbuf;
        ln_kernel<<<lnBlocks, 256, 0, stream>>>(xin, ln1g + l * DIMC, ln1b + l * DIMC, h, N);
        // QKV: OUT=384 -> 6 ntiles, 942 blocks
        mfma_gemm<0><<<mt * 6, 256, 0, stream>>>(
            h, wqkvB + (size_t)l * QKVC * DIMC, bqkvF + l * QKVC, nullptr,
            qkv, N, DIMC, QKVC, mt, 6);
        attn_kernel<<<attnBlocks, 256, 0, stream>>>(qkv, rowptr, srcperm, agg, N);
        // out-proj: OUT=256, K=128 -> 628 blocks
        mfma_gemm<2><<<mt * 4, 256, 0, stream>>>(
            agg, woB + (size_t)l * DIMC * INNERC, bo + l * DIMC, xin,
            xbuf, N, INNERC, DIMC, mt, 4);
        ln_kernel<<<lnBlocks, 256, 0, stream>>>(xbuf, ln2g + l * DIMC, ln2b + l * DIMC, h, N);
        // FF1: OUT=1024 -> 16 ntiles, 2512 blocks
        mfma_gemm<1><<<mt * 16, 256, 0, stream>>>(
            h, w1B + (size_t)l * 1024 * DIMC, b1 + l * 1024, nullptr,
            u, N, DIMC, 1024, mt, 16);
        float* xout = (l == 3) ? (float*)d_out : xbuf;
        // FF2: OUT=256, K=1024 -> 628 blocks, 16 K-steps (pipeline fills)
        mfma_gemm<2><<<mt * 4, 256, 0, stream>>>(
            u, w2B + (size_t)l * DIMC * 1024, b2 + l * DIMC, xbuf,
            xout, N, 1024, DIMC, mt, 4);
    }
}

// Round 12
// 571.313 us; speedup vs baseline: 1.7450x; 1.0606x over previous
//
#include <hip/hip_runtime.h>
#include <hip/hip_bf16.h>
#include <math.h>

#define DIMC 256
#define INNERC 128
#define HEADSC 4
#define DHC 32
#define QKVC 384

typedef __attribute__((ext_vector_type(8))) short bf16frag;   // 8 bf16 = 4 VGPRs
typedef __attribute__((ext_vector_type(4))) float f32x4;

__device__ __forceinline__ float gelu_exact(float x) {
    return 0.5f * x * (1.0f + erff(x * 0.70710678118654752f));
}

__device__ __forceinline__ float b2f(short s) {
    return __uint_as_float(((unsigned)(unsigned short)s) << 16);
}

__device__ __forceinline__ void gload_lds16(const void* g, void* l) {
    __builtin_amdgcn_global_load_lds(
        (const __attribute__((address_space(1))) void*)g,
        (__attribute__((address_space(3))) void*)l, 16, 0, 0);
}

// ---------------- LayerNorm: one WAVE per row, no barriers ----------------
__global__ __launch_bounds__(256)
void ln_kernel(const float* __restrict__ x, const float* __restrict__ g,
               const float* __restrict__ b, __hip_bfloat16* __restrict__ out,
               int N)
{
    int row = blockIdx.x * 4 + (threadIdx.x >> 6);
    if (row >= N) return;
    int lane = threadIdx.x & 63;
    float4 v = *(const float4*)(x + (size_t)row * DIMC + lane * 4);
    float s = v.x + v.y + v.z + v.w;
    float s2 = v.x * v.x + v.y * v.y + v.z * v.z + v.w * v.w;
#pragma unroll
    for (int off = 32; off; off >>= 1) {
        s += __shfl_xor(s, off);
        s2 += __shfl_xor(s2, off);
    }
    float mean = s * (1.f / DIMC);
    float var = s2 * (1.f / DIMC) - mean * mean;
    float rs = rsqrtf(var + 1e-5f);
    float4 gv = *(const float4*)(g + lane * 4);
    float4 bv = *(const float4*)(b + lane * 4);
    __hip_bfloat16 o[4];
    o[0] = __float2bfloat16((v.x - mean) * rs * gv.x + bv.x);
    o[1] = __float2bfloat16((v.y - mean) * rs * gv.y + bv.y);
    o[2] = __float2bfloat16((v.z - mean) * rs * gv.z + bv.z);
    o[3] = __float2bfloat16((v.w - mean) * rs * gv.w + bv.w);
    *(short4*)(out + (size_t)row * DIMC + lane * 4) = *(short4*)o;
}

// ---------------- fp32 -> bf16 convert (n % 4 == 0) ----------------
__global__ void f2b_kernel(const float* __restrict__ src,
                           __hip_bfloat16* __restrict__ dst, int n)
{
    int i = (blockIdx.x * blockDim.x + threadIdx.x) * 4;
    if (i < n) {
        float4 v = *(const float4*)(src + i);
        dst[i + 0] = __float2bfloat16(v.x);
        dst[i + 1] = __float2bfloat16(v.y);
        dst[i + 2] = __float2bfloat16(v.z);
        dst[i + 3] = __float2bfloat16(v.w);
    }
}

// ---------------- pack wq/wk/wv -> wqkv bf16 [4][384][256], biases [4][384] ----
__global__ __launch_bounds__(256)
void packqkv_kernel(const float* __restrict__ wq, const float* __restrict__ wk,
                    const float* __restrict__ wv, const float* __restrict__ bq,
                    const float* __restrict__ bk, const float* __restrict__ bv,
                    __hip_bfloat16* __restrict__ wqkv, float* __restrict__ bqkv)
{
    int row = blockIdx.x;                 // 0 .. 4*384-1
    int l = row / QKVC, c = row % QKVC;
    int which = c >> 7, cc = c & 127;
    const float* srcw = which == 0 ? wq : which == 1 ? wk : wv;
    const float* srcb = which == 0 ? bq : which == 1 ? bk : bv;
    srcw += ((size_t)l * INNERC + cc) * DIMC;
    wqkv[(size_t)row * DIMC + threadIdx.x] = __float2bfloat16(srcw[threadIdx.x]);
    if (threadIdx.x == 0) bqkv[row] = srcb[l * INNERC + cc];
}

// ---------------- MFMA GEMM v5: 512 thr, 128x128, dbuf + counted vmcnt ------
// C[M][OUT] = A[M][K] @ W[OUT][K]^T + bias.  BM=128, BK=64, BN=128.
// 8 waves (2x4): wave tile 64x32, acc 4x2 f32x4 (32 AGPR), 16 MFMA : 12 ds_read.
// LDS = 2x16K A + 2x16K W = 64KB -> 2 blocks/CU x 8 waves = 4 waves/SIMD.
// Staging: 4 loads/thread (2 A + 2 W); raw s_barrier + s_waitcnt vmcnt(4)
// keeps next-tile prefetch in flight across the barrier (m218 mechanism).
// Staging unconditional (rows clamped to M-1) so the vmcnt count is exact.
// EPI: 0 = bias -> bf16; 1 = bias+gelu -> bf16; 2 = bias+res -> fp32.
template<int EPI>
__global__ __launch_bounds__(512)
void mfma_gemm(const __hip_bfloat16* __restrict__ A,
               const __hip_bfloat16* __restrict__ W,
               const float* __restrict__ bias, const float* __restrict__ res,
               void* __restrict__ Cout, int M, int K, int OUT,
               int mtiles, int ntiles)
{
    constexpr int ASZ = 128 * 128;          // one A buf (16KB)
    constexpr int WSZ = 128 * 128;          // one W buf (16KB)
    __shared__ char lds[2 * ASZ + 2 * WSZ];

    int nwg = mtiles * ntiles;
    int orig = blockIdx.x;
    int q = nwg >> 3, r = nwg & 7;
    int xcd = orig & 7, loc = orig >> 3;
    int wgid = (xcd < r ? xcd * (q + 1) : r * (q + 1) + (xcd - r) * q) + loc;
    int bm = (wgid / ntiles) * 128;
    int bn = (wgid % ntiles) * 128;

    int tid = threadIdx.x;
    int lane = tid & 63;
    int w = tid >> 6;                        // 0..7
    int wr = w >> 2, wc = w & 3;             // 2 x 4 wave grid
    int l15 = lane & 15, l4 = lane >> 4;

    f32x4 acc[4][2] = {};

    auto stage = [&](int t, int b) {
        int k0 = t * 64;
        char* Asb = lds + b * ASZ;
        char* Wsb = lds + 2 * ASZ + b * WSZ;
#pragma unroll
        for (int it = 0; it < 2; ++it) {             // A: 2 loads/thread
            int chunk = it * 512 + tid;
            int rr = chunk >> 3;
            int sc = (chunk & 7) ^ (rr & 7);
            int grow = min(bm + rr, M - 1);          // clamp: ALWAYS issue
            gload_lds16((const char*)A + ((size_t)grow * K + k0) * 2 + sc * 16,
                        Asb + chunk * 16);
        }
#pragma unroll
        for (int it = 0; it < 2; ++it) {             // W: 2 loads/thread
            int chunk = it * 512 + tid;
            int rr = chunk >> 3;
            int sc = (chunk & 7) ^ (rr & 7);
            gload_lds16((const char*)W + ((size_t)(bn + rr) * K + k0) * 2 + sc * 16,
                        Wsb + chunk * 16);
        }
    };

    int nk = K >> 6;
    stage(0, 0);
    for (int t = 0; t < nk; ++t) {
        int cur = t & 1;
        if (t + 1 < nk) {
            stage(t + 1, cur ^ 1);                   // prefetch into other buf
            asm volatile("s_waitcnt vmcnt(4)" ::: "memory");   // tile t only
        } else {
            asm volatile("s_waitcnt vmcnt(0)" ::: "memory");
        }
        __builtin_amdgcn_s_barrier();                // tile t visible, no drain
        char* As = lds + cur * ASZ;
        char* Ws = lds + 2 * ASZ + cur * WSZ;
#pragma unroll
        for (int s = 0; s < 2; ++s) {
            bf16frag af[4], bfr[2];
            int kb = s * 64 + (l4 << 4);
#pragma unroll
            for (int m = 0; m < 4; ++m) {
                int ar = wr * 64 + m * 16 + l15;
                af[m] = *(const bf16frag*)(As + ar * 128 + (kb ^ ((ar & 7) << 4)));
            }
#pragma unroll
            for (int n = 0; n < 2; ++n) {
                int br = wc * 32 + n * 16 + l15;
                bfr[n] = *(const bf16frag*)(Ws + br * 128 + (kb ^ ((br & 7) << 4)));
            }
#pragma unroll
            for (int m = 0; m < 4; ++m)
#pragma unroll
                for (int n = 0; n < 2; ++n)
                    acc[m][n] = __builtin_amdgcn_mfma_f32_16x16x32_bf16(
                        af[m], bfr[n], acc[m][n], 0, 0, 0);
        }
        __builtin_amdgcn_s_barrier();                // all reads of buf done (WAR)
    }

#pragma unroll
    for (int m = 0; m < 4; ++m)
#pragma unroll
        for (int rr = 0; rr < 4; ++rr) {
            int grow = bm + wr * 64 + m * 16 + (l4 << 2) + rr;
            if (grow < M) {
#pragma unroll
                for (int n = 0; n < 2; ++n) {
                    int gcol = bn + wc * 32 + n * 16 + l15;
                    float val = acc[m][n][rr] + bias[gcol];
                    if (EPI == 1) val = gelu_exact(val);
                    if (EPI == 2) {
                        val += res[(size_t)grow * OUT + gcol];
                        ((float*)Cout)[(size_t)grow * OUT + gcol] = val;
                    } else {
                        ((__hip_bfloat16*)Cout)[(size_t)grow * OUT + gcol] =
                            __float2bfloat16(val);
                    }
                }
            }
        }
}

// ---------------- CSR build ----------------
__global__ void count_kernel(const int* __restrict__ dst, int* __restrict__ count, int E)
{
    int e = blockIdx.x * blockDim.x + threadIdx.x;
    if (e < E) atomicAdd(&count[dst[e]], 1);
}

__global__ __launch_bounds__(1024)
void scan_kernel(const int* __restrict__ count, int* __restrict__ rowptr, int N)
{
    __shared__ int sdata[1024];
    __shared__ int carry_s;
    int t = threadIdx.x;
    if (t == 0) { carry_s = 0; rowptr[0] = 0; }
    __syncthreads();
    for (int base = 0; base < N; base += 1024) {
        int idx = base + t;
        int v = (idx < N) ? count[idx] : 0;
        sdata[t] = v;
        __syncthreads();
        for (int off = 1; off < 1024; off <<= 1) {
            int add = (t >= off) ? sdata[t - off] : 0;
            __syncthreads();
            sdata[t] += add;
            __syncthreads();
        }
        if (idx < N) rowptr[idx + 1] = carry_s + sdata[t];
        __syncthreads();
        if (t == 0) carry_s += sdata[1023];
        __syncthreads();
    }
}

__global__ void scatter_kernel(const int* __restrict__ src, const int* __restrict__ dst,
                               const int* __restrict__ rowptr, int* __restrict__ cursor,
                               int* __restrict__ srcperm, int E)
{
    int e = blockIdx.x * blockDim.x + threadIdx.x;
    if (e < E) {
        int d = dst[e];
        int pos = rowptr[d] + atomicAdd(&cursor[d], 1);
        srcperm[pos] = src[e];
    }
}

// ---------------- Attention: one WAVE per node, ILP-restructured ------------
__global__ __launch_bounds__(256)
void attn_kernel(const __hip_bfloat16* __restrict__ qkv, const int* __restrict__ rowptr,
                 const int* __restrict__ srcperm, __hip_bfloat16* __restrict__ agg,
                 int N)
{
    int wid = (blockIdx.x * 256 + threadIdx.x) >> 6;   // node index
    if (wid >= N) return;
    int lane = threadIdx.x & 63;
    int h = lane >> 4, u = lane & 15;
    int i = wid;
    int beg = rowptr[i], deg = rowptr[i + 1] - beg;
    const short* base = (const short*)qkv;
    const float scale = 0.17677669529663687f; // 1/sqrt(32)

    bf16frag qf[4];
    const short* qr = base + (size_t)i * QKVC + h * 32;
#pragma unroll
    for (int c = 0; c < 4; ++c) qf[c] = *(const bf16frag*)(qr + c * 8);

    float m_run = -3.4e38f, d_run = 0.f;
    float accx = 0.f, accy = 0.f;

    int j = (u < deg) ? srcperm[beg + u] : i;

    for (int c0 = 0; c0 < deg; c0 += 16) {
        int cn = min(16, deg - c0);
        bool valid = (u < cn);

        const short* kr = base + (size_t)j * QKVC + 128 + h * 32;
        bf16frag kf[4];
#pragma unroll
        for (int c = 0; c < 4; ++c) kf[c] = *(const bf16frag*)(kr + c * 8);

        int nxt = c0 + 16 + u;
        int jn = (nxt < deg) ? srcperm[beg + nxt] : i;

        float dot = 0.f;
#pragma unroll
        for (int c = 0; c < 4; ++c)
#pragma unroll
            for (int e = 0; e < 8; ++e)
                dot += b2f(qf[c][e]) * b2f(kf[c][e]);
        float alpha = valid ? dot * scale : -3.4e38f;

        float cm = alpha;
#pragma unroll
        for (int off = 8; off; off >>= 1) cm = fmaxf(cm, __shfl_xor(cm, off));
        float m_new = fmaxf(m_run, cm);
        float rescale = expf(m_run - m_new);
        float w = valid ? expf(alpha - m_new) : 0.f;
        float dsum = w;
#pragma unroll
        for (int off = 8; off; off >>= 1) dsum += __shfl_xor(dsum, off);
        d_run = d_run * rescale + dsum;
        m_run = m_new;
        accx *= rescale;
        accy *= rescale;

        float wes[16];
        unsigned vws[16];
#pragma unroll
        for (int e = 0; e < 16; ++e) {
            wes[e] = __shfl(w, h * 16 + e);
            int je = __shfl(j, h * 16 + e);        // invalid slots -> row i
            vws[e] = *(const unsigned*)(base + (size_t)je * QKVC + 256 + h * 32 + u * 2);
        }
#pragma unroll
        for (int e = 0; e < 16; ++e) {
            accx += wes[e] * b2f((short)(vws[e] & 0xffff));
            accy += wes[e] * b2f((short)(vws[e] >> 16));
        }
        j = jn;
    }

    float inv = 1.f / (d_run + 1e-16f);
    __hip_bfloat16* outp = agg + (size_t)i * INNERC + h * 32 + u * 2;
    outp[0] = __float2bfloat16(accx * inv);
    outp[1] = __float2bfloat16(accy * inv);
}

// ---------------- Launch ----------------
extern "C" void kernel_launch(void* const* d_in, const int* in_sizes, int n_in,
                              void* d_out, int out_size, void* d_ws, size_t ws_size,
                              hipStream_t stream)
{
    const float* x    = (const float*)d_in[0];
    const int*   ei   = (const int*)  d_in[1];
    const float* ln1g = (const float*)d_in[2];
    const float* ln1b = (const float*)d_in[3];
    const float* wq   = (const float*)d_in[4];
    const float* bq   = (const float*)d_in[5];
    const float* wk   = (const float*)d_in[6];
    const float* bk   = (const float*)d_in[7];
    const float* wv   = (const float*)d_in[8];
    const float* bv   = (const float*)d_in[9];
    const float* wo   = (const float*)d_in[10];
    const float* bo   = (const float*)d_in[11];
    const float* ln2g = (const float*)d_in[12];
    const float* ln2b = (const float*)d_in[13];
    const float* w1   = (const float*)d_in[14];
    const float* b1   = (const float*)d_in[15];
    const float* w2   = (const float*)d_in[16];
    const float* b2   = (const float*)d_in[17];

    const int N = in_sizes[0] / DIMC;   // 20000
    const int E = in_sizes[1] / 2;      // 320000
    const int* srcIdx = ei;
    const int* dstIdx = ei + E;

    char* p = (char*)d_ws;
    auto alloc = [&](size_t bytes) {
        char* r = p;
        p += (bytes + 255) & ~(size_t)255;
        return r;
    };
    float*          xbuf   = (float*)alloc((size_t)N * DIMC * 4);
    __hip_bfloat16* h      = (__hip_bfloat16*)alloc((size_t)N * DIMC * 2);
    __hip_bfloat16* qkv    = (__hip_bfloat16*)alloc((size_t)N * QKVC * 2);
    __hip_bfloat16* agg    = (__hip_bfloat16*)alloc((size_t)N * INNERC * 2);
    __hip_bfloat16* u      = (__hip_bfloat16*)alloc((size_t)N * 1024 * 2);
    int*            rowptr = (int*)alloc((size_t)(N + 1) * 4);
    int*            cnt    = (int*)alloc((size_t)N * 4);
    int*            srcperm= (int*)alloc((size_t)E * 4);
    __hip_bfloat16* wqkvB  = (__hip_bfloat16*)alloc((size_t)4 * QKVC * DIMC * 2);
    float*          bqkvF  = (float*)alloc((size_t)4 * QKVC * 4);
    __hip_bfloat16* woB    = (__hip_bfloat16*)alloc((size_t)4 * DIMC * INNERC * 2);
    __hip_bfloat16* w1B    = (__hip_bfloat16*)alloc((size_t)4 * 1024 * DIMC * 2);
    __hip_bfloat16* w2B    = (__hip_bfloat16*)alloc((size_t)4 * DIMC * 1024 * 2);

    // Weight conversion (per-call, deterministic)
    packqkv_kernel<<<4 * QKVC, 256, 0, stream>>>(wq, wk, wv, bq, bk, bv, wqkvB, bqkvF);
    {
        int n = 4 * DIMC * INNERC;
        f2b_kernel<<<(n / 4 + 255) / 256, 256, 0, stream>>>(wo, woB, n);
        n = 4 * 1024 * DIMC;
        f2b_kernel<<<(n / 4 + 255) / 256, 256, 0, stream>>>(w1, w1B, n);
        f2b_kernel<<<(n / 4 + 255) / 256, 256, 0, stream>>>(w2, w2B, n);
    }

    // CSR build
    hipMemsetAsync(cnt, 0, (size_t)N * 4, stream);
    count_kernel<<<(E + 255) / 256, 256, 0, stream>>>(dstIdx, cnt, E);
    scan_kernel<<<1, 1024, 0, stream>>>(cnt, rowptr, N);
    hipMemsetAsync(cnt, 0, (size_t)N * 4, stream);
    scatter_kernel<<<(E + 255) / 256, 256, 0, stream>>>(srcIdx, dstIdx, rowptr, cnt, srcperm, E);

    int mt = (N + 127) / 128;        // 157
    int lnBlocks = (N + 3) / 4;      // 5000
    int attnBlocks = (N * 64 + 255) / 256;
    for (int l = 0; l < 4; ++l) {
        const float* xin = (l == 0) ? x : xbuf;
        ln_kernel<<<lnBlocks, 256, 0, stream>>>(xin, ln1g + l * DIMC, ln1b + l * DIMC, h, N);
        // QKV: OUT=384 -> 3 ntiles, 471 blocks
        mfma_gemm<0><<<mt * 3, 512, 0, stream>>>(
            h, wqkvB + (size_t)l * QKVC * DIMC, bqkvF + l * QKVC, nullptr,
            qkv, N, DIMC, QKVC, mt, 3);
        attn_kernel<<<attnBlocks, 256, 0, stream>>>(qkv, rowptr, srcperm, agg, N);
        // out-proj: OUT=256, K=128 -> 314 blocks
        mfma_gemm<2><<<mt * 2, 512, 0, stream>>>(
            agg, woB + (size_t)l * DIMC * INNERC, bo + l * DIMC, xin,
            xbuf, N, INNERC, DIMC, mt, 2);
        ln_kernel<<<lnBlocks, 256, 0, stream>>>(xbuf, ln2g + l * DIMC, ln2b + l * DIMC, h, N);
        // FF1: OUT=1024 -> 8 ntiles, 1256 blocks
        mfma_gemm<1><<<mt * 8, 512, 0, stream>>>(
            h, w1B + (size_t)l * 1024 * DIMC, b1 + l * 1024, nullptr,
            u, N, DIMC, 1024, mt, 8);
        float* xout = (l == 3) ? (float*)d_out : xbuf;
        // FF2: OUT=256, K=1024 -> 314 blocks, 16 K-steps (pipeline fills)
        mfma_gemm<2><<<mt * 2, 512, 0, stream>>>(
            u, w2B + (size_t)l * DIMC * 1024, b2 + l * DIMC, xbuf,
            xout, N, 1024, DIMC, mt, 2);
    }
}

// Round 13
// 545.700 us; speedup vs baseline: 1.8269x; 1.0469x over previous
//
#include <hip/hip_runtime.h>
#include <hip/hip_bf16.h>
#include <math.h>

#define DIMC 256
#define INNERC 128
#define HEADSC 4
#define DHC 32
#define QKVC 384

typedef __attribute__((ext_vector_type(8))) short bf16frag;   // 8 bf16 = 4 VGPRs
typedef __attribute__((ext_vector_type(4))) float f32x4;

__device__ __forceinline__ float gelu_exact(float x) {
    return 0.5f * x * (1.0f + erff(x * 0.70710678118654752f));
}

__device__ __forceinline__ float b2f(short s) {
    return __uint_as_float(((unsigned)(unsigned short)s) << 16);
}

__device__ __forceinline__ void gload_lds16(const void* g, void* l) {
    __builtin_amdgcn_global_load_lds(
        (const __attribute__((address_space(1))) void*)g,
        (__attribute__((address_space(3))) void*)l, 16, 0, 0);
}

// ---------------- LayerNorm: one WAVE per row, no barriers ----------------
__global__ __launch_bounds__(256)
void ln_kernel(const float* __restrict__ x, const float* __restrict__ g,
               const float* __restrict__ b, __hip_bfloat16* __restrict__ out,
               int N)
{
    int row = blockIdx.x * 4 + (threadIdx.x >> 6);
    if (row >= N) return;
    int lane = threadIdx.x & 63;
    float4 v = *(const float4*)(x + (size_t)row * DIMC + lane * 4);
    float s = v.x + v.y + v.z + v.w;
    float s2 = v.x * v.x + v.y * v.y + v.z * v.z + v.w * v.w;
#pragma unroll
    for (int off = 32; off; off >>= 1) {
        s += __shfl_xor(s, off);
        s2 += __shfl_xor(s2, off);
    }
    float mean = s * (1.f / DIMC);
    float var = s2 * (1.f / DIMC) - mean * mean;
    float rs = rsqrtf(var + 1e-5f);
    float4 gv = *(const float4*)(g + lane * 4);
    float4 bv = *(const float4*)(b + lane * 4);
    __hip_bfloat16 o[4];
    o[0] = __float2bfloat16((v.x - mean) * rs * gv.x + bv.x);
    o[1] = __float2bfloat16((v.y - mean) * rs * gv.y + bv.y);
    o[2] = __float2bfloat16((v.z - mean) * rs * gv.z + bv.z);
    o[3] = __float2bfloat16((v.w - mean) * rs * gv.w + bv.w);
    *(short4*)(out + (size_t)row * DIMC + lane * 4) = *(short4*)o;
}

// ---------------- fp32 -> bf16 convert (n % 4 == 0) ----------------
__global__ void f2b_kernel(const float* __restrict__ src,
                           __hip_bfloat16* __restrict__ dst, int n)
{
    int i = (blockIdx.x * blockDim.x + threadIdx.x) * 4;
    if (i < n) {
        float4 v = *(const float4*)(src + i);
        dst[i + 0] = __float2bfloat16(v.x);
        dst[i + 1] = __float2bfloat16(v.y);
        dst[i + 2] = __float2bfloat16(v.z);
        dst[i + 3] = __float2bfloat16(v.w);
    }
}

// ---------------- pack wq/wk/wv -> wqkv bf16 [4][384][256], biases [4][384] ----
__global__ __launch_bounds__(256)
void packqkv_kernel(const float* __restrict__ wq, const float* __restrict__ wk,
                    const float* __restrict__ wv, const float* __restrict__ bq,
                    const float* __restrict__ bk, const float* __restrict__ bv,
                    __hip_bfloat16* __restrict__ wqkv, float* __restrict__ bqkv)
{
    int row = blockIdx.x;                 // 0 .. 4*384-1
    int l = row / QKVC, c = row % QKVC;
    int which = c >> 7, cc = c & 127;
    const float* srcw = which == 0 ? wq : which == 1 ? wk : wv;
    const float* srcb = which == 0 ? bq : which == 1 ? bk : bv;
    srcw += ((size_t)l * INNERC + cc) * DIMC;
    wqkv[(size_t)row * DIMC + threadIdx.x] = __float2bfloat16(srcw[threadIdx.x]);
    if (threadIdx.x == 0) bqkv[row] = srcb[l * INNERC + cc];
}

// ---------------- MFMA GEMM v5: 512 thr, 128x128, dbuf + counted vmcnt ------
// (unchanged from R12 — proven)
template<int EPI>
__global__ __launch_bounds__(512)
void mfma_gemm(const __hip_bfloat16* __restrict__ A,
               const __hip_bfloat16* __restrict__ W,
               const float* __restrict__ bias, const float* __restrict__ res,
               void* __restrict__ Cout, int M, int K, int OUT,
               int mtiles, int ntiles)
{
    constexpr int ASZ = 128 * 128;          // one A buf (16KB)
    constexpr int WSZ = 128 * 128;          // one W buf (16KB)
    __shared__ char lds[2 * ASZ + 2 * WSZ];

    int nwg = mtiles * ntiles;
    int orig = blockIdx.x;
    int q = nwg >> 3, r = nwg & 7;
    int xcd = orig & 7, loc = orig >> 3;
    int wgid = (xcd < r ? xcd * (q + 1) : r * (q + 1) + (xcd - r) * q) + loc;
    int bm = (wgid / ntiles) * 128;
    int bn = (wgid % ntiles) * 128;

    int tid = threadIdx.x;
    int lane = tid & 63;
    int w = tid >> 6;                        // 0..7
    int wr = w >> 2, wc = w & 3;             // 2 x 4 wave grid
    int l15 = lane & 15, l4 = lane >> 4;

    f32x4 acc[4][2] = {};

    auto stage = [&](int t, int b) {
        int k0 = t * 64;
        char* Asb = lds + b * ASZ;
        char* Wsb = lds + 2 * ASZ + b * WSZ;
#pragma unroll
        for (int it = 0; it < 2; ++it) {             // A: 2 loads/thread
            int chunk = it * 512 + tid;
            int rr = chunk >> 3;
            int sc = (chunk & 7) ^ (rr & 7);
            int grow = min(bm + rr, M - 1);          // clamp: ALWAYS issue
            gload_lds16((const char*)A + ((size_t)grow * K + k0) * 2 + sc * 16,
                        Asb + chunk * 16);
        }
#pragma unroll
        for (int it = 0; it < 2; ++it) {             // W: 2 loads/thread
            int chunk = it * 512 + tid;
            int rr = chunk >> 3;
            int sc = (chunk & 7) ^ (rr & 7);
            gload_lds16((const char*)W + ((size_t)(bn + rr) * K + k0) * 2 + sc * 16,
                        Wsb + chunk * 16);
        }
    };

    int nk = K >> 6;
    stage(0, 0);
    for (int t = 0; t < nk; ++t) {
        int cur = t & 1;
        if (t + 1 < nk) {
            stage(t + 1, cur ^ 1);                   // prefetch into other buf
            asm volatile("s_waitcnt vmcnt(4)" ::: "memory");   // tile t only
        } else {
            asm volatile("s_waitcnt vmcnt(0)" ::: "memory");
        }
        __builtin_amdgcn_s_barrier();                // tile t visible, no drain
        char* As = lds + cur * ASZ;
        char* Ws = lds + 2 * ASZ + cur * WSZ;
#pragma unroll
        for (int s = 0; s < 2; ++s) {
            bf16frag af[4], bfr[2];
            int kb = s * 64 + (l4 << 4);
#pragma unroll
            for (int m = 0; m < 4; ++m) {
                int ar = wr * 64 + m * 16 + l15;
                af[m] = *(const bf16frag*)(As + ar * 128 + (kb ^ ((ar & 7) << 4)));
            }
#pragma unroll
            for (int n = 0; n < 2; ++n) {
                int br = wc * 32 + n * 16 + l15;
                bfr[n] = *(const bf16frag*)(Ws + br * 128 + (kb ^ ((br & 7) << 4)));
            }
#pragma unroll
            for (int m = 0; m < 4; ++m)
#pragma unroll
                for (int n = 0; n < 2; ++n)
                    acc[m][n] = __builtin_amdgcn_mfma_f32_16x16x32_bf16(
                        af[m], bfr[n], acc[m][n], 0, 0, 0);
        }
        __builtin_amdgcn_s_barrier();                // all reads of buf done (WAR)
    }

#pragma unroll
    for (int m = 0; m < 4; ++m)
#pragma unroll
        for (int rr = 0; rr < 4; ++rr) {
            int grow = bm + wr * 64 + m * 16 + (l4 << 2) + rr;
            if (grow < M) {
#pragma unroll
                for (int n = 0; n < 2; ++n) {
                    int gcol = bn + wc * 32 + n * 16 + l15;
                    float val = acc[m][n][rr] + bias[gcol];
                    if (EPI == 1) val = gelu_exact(val);
                    if (EPI == 2) {
                        val += res[(size_t)grow * OUT + gcol];
                        ((float*)Cout)[(size_t)grow * OUT + gcol] = val;
                    } else {
                        ((__hip_bfloat16*)Cout)[(size_t)grow * OUT + gcol] =
                            __float2bfloat16(val);
                    }
                }
            }
        }
}

// ---------------- CSR build: count + hierarchical scan + scatter ------------
__global__ void count_kernel(const int* __restrict__ dst, int* __restrict__ count, int E)
{
    int e = blockIdx.x * blockDim.x + threadIdx.x;
    if (e < E) atomicAdd(&count[dst[e]], 1);
}

// per-block inclusive scan of 1024 counts -> rowptr[idx+1]; block sum -> bsum[b]
__global__ __launch_bounds__(1024)
void scanA_kernel(const int* __restrict__ count, int* __restrict__ rowptr,
                  int* __restrict__ bsum, int N)
{
    __shared__ int sdata[1024];
    int b = blockIdx.x, t = threadIdx.x;
    int idx = b * 1024 + t;
    int v = (idx < N) ? count[idx] : 0;
    sdata[t] = v;
    __syncthreads();
    for (int off = 1; off < 1024; off <<= 1) {
        int add = (t >= off) ? sdata[t - off] : 0;
        __syncthreads();
        sdata[t] += add;
        __syncthreads();
    }
    if (idx < N) rowptr[idx + 1] = sdata[t];
    if (t == 1023) bsum[b] = sdata[1023];
}

// single-wave inclusive scan of nb (<=64) block sums
__global__ void scanB_kernel(int* __restrict__ bsum, int nb)
{
    int t = threadIdx.x;
    int v = (t < nb) ? bsum[t] : 0;
#pragma unroll
    for (int off = 1; off < 64; off <<= 1) {
        int u = __shfl_up(v, off);
        if (t >= off) v += u;
    }
    if (t < nb) bsum[t] = v;
}

__global__ __launch_bounds__(1024)
void scanC_kernel(int* __restrict__ rowptr, const int* __restrict__ bsum, int N)
{
    int b = blockIdx.x, t = threadIdx.x;
    int idx = b * 1024 + t;
    if (idx == 0) rowptr[0] = 0;
    if (idx < N && b > 0) rowptr[idx + 1] += bsum[b - 1];
}

__global__ void scatter_kernel(const int* __restrict__ src, const int* __restrict__ dst,
                               const int* __restrict__ rowptr, int* __restrict__ cursor,
                               int* __restrict__ srcperm, int E)
{
    int e = blockIdx.x * blockDim.x + threadIdx.x;
    if (e < E) {
        int d = dst[e];
        int pos = rowptr[d] + atomicAdd(&cursor[d], 1);
        srcperm[pos] = src[e];
    }
}

// ---------------- Attention: wave/node, cross-chunk K prefetch --------------
// Lane = h*16+u. Chunk of 16 edges. Next chunk's K rows are loaded into regs
// right after jn arrives, BEFORE the V phase, so K-gather latency hides under
// the 16 V gathers. __expf for the softmax exponentials.
__global__ __launch_bounds__(256)
void attn_kernel(const __hip_bfloat16* __restrict__ qkv, const int* __restrict__ rowptr,
                 const int* __restrict__ srcperm, __hip_bfloat16* __restrict__ agg,
                 int N)
{
    int wid = (blockIdx.x * 256 + threadIdx.x) >> 6;   // node index
    if (wid >= N) return;
    int lane = threadIdx.x & 63;
    int h = lane >> 4, u = lane & 15;
    int i = wid;
    int beg = rowptr[i], deg = rowptr[i + 1] - beg;
    const short* base = (const short*)qkv;
    const float scale = 0.17677669529663687f; // 1/sqrt(32)

    bf16frag qf[4];
    const short* qr = base + (size_t)i * QKVC + h * 32;
#pragma unroll
    for (int c = 0; c < 4; ++c) qf[c] = *(const bf16frag*)(qr + c * 8);

    float m_run = -3.4e38f, d_run = 0.f;
    float accx = 0.f, accy = 0.f;

    int j = (u < deg) ? srcperm[beg + u] : i;
    bf16frag kf[4];
    {
        const short* kr = base + (size_t)j * QKVC + 128 + h * 32;
#pragma unroll
        for (int c = 0; c < 4; ++c) kf[c] = *(const bf16frag*)(kr + c * 8);
    }

    for (int c0 = 0; c0 < deg; c0 += 16) {
        int cn = min(16, deg - c0);
        bool valid = (u < cn);

        // ---- next chunk's edge index ----
        int nxt = c0 + 16 + u;
        int jn = (nxt < deg) ? srcperm[beg + nxt] : i;

        // ---- dot (uses prefetched kf) ----
        float dot = 0.f;
#pragma unroll
        for (int c = 0; c < 4; ++c)
#pragma unroll
            for (int e = 0; e < 8; ++e)
                dot += b2f(qf[c][e]) * b2f(kf[c][e]);
        float alpha = valid ? dot * scale : -3.4e38f;

        // ---- per-head online softmax (16-lane group reduce) ----
        float cm = alpha;
#pragma unroll
        for (int off = 8; off; off >>= 1) cm = fmaxf(cm, __shfl_xor(cm, off));
        float m_new = fmaxf(m_run, cm);
        float rescale = __expf(m_run - m_new);
        float w = valid ? __expf(alpha - m_new) : 0.f;
        float dsum = w;
#pragma unroll
        for (int off = 8; off; off >>= 1) dsum += __shfl_xor(dsum, off);
        d_run = d_run * rescale + dsum;
        m_run = m_new;
        accx *= rescale;
        accy *= rescale;

        // ---- prefetch next chunk's K rows (overlaps with V phase below) ----
        bf16frag kfn[4];
        {
            const short* krn = base + (size_t)jn * QKVC + 128 + h * 32;
#pragma unroll
            for (int c = 0; c < 4; ++c) kfn[c] = *(const bf16frag*)(krn + c * 8);
        }

        // ---- V phase: branchless fixed-16 unroll, all gathers in flight ----
        float wes[16];
        unsigned vws[16];
#pragma unroll
        for (int e = 0; e < 16; ++e) {
            wes[e] = __shfl(w, h * 16 + e);
            int je = __shfl(j, h * 16 + e);        // invalid slots -> row i
            vws[e] = *(const unsigned*)(base + (size_t)je * QKVC + 256 + h * 32 + u * 2);
        }
#pragma unroll
        for (int e = 0; e < 16; ++e) {
            accx += wes[e] * b2f((short)(vws[e] & 0xffff));
            accy += wes[e] * b2f((short)(vws[e] >> 16));
        }
        j = jn;
#pragma unroll
        for (int c = 0; c < 4; ++c) kf[c] = kfn[c];
    }

    float inv = 1.f / (d_run + 1e-16f);
    __hip_bfloat16* outp = agg + (size_t)i * INNERC + h * 32 + u * 2;
    outp[0] = __float2bfloat16(accx * inv);
    outp[1] = __float2bfloat16(accy * inv);
}

// ---------------- Launch ----------------
extern "C" void kernel_launch(void* const* d_in, const int* in_sizes, int n_in,
                              void* d_out, int out_size, void* d_ws, size_t ws_size,
                              hipStream_t stream)
{
    const float* x    = (const float*)d_in[0];
    const int*   ei   = (const int*)  d_in[1];
    const float* ln1g = (const float*)d_in[2];
    const float* ln1b = (const float*)d_in[3];
    const float* wq   = (const float*)d_in[4];
    const float* bq   = (const float*)d_in[5];
    const float* wk   = (const float*)d_in[6];
    const float* bk   = (const float*)d_in[7];
    const float* wv   = (const float*)d_in[8];
    const float* bv   = (const float*)d_in[9];
    const float* wo   = (const float*)d_in[10];
    const float* bo   = (const float*)d_in[11];
    const float* ln2g = (const float*)d_in[12];
    const float* ln2b = (const float*)d_in[13];
    const float* w1   = (const float*)d_in[14];
    const float* b1   = (const float*)d_in[15];
    const float* w2   = (const float*)d_in[16];
    const float* b2   = (const float*)d_in[17];

    const int N = in_sizes[0] / DIMC;   // 20000
    const int E = in_sizes[1] / 2;      // 320000
    const int* srcIdx = ei;
    const int* dstIdx = ei + E;

    char* p = (char*)d_ws;
    auto alloc = [&](size_t bytes) {
        char* r = p;
        p += (bytes + 255) & ~(size_t)255;
        return r;
    };
    float*          xbuf   = (float*)alloc((size_t)N * DIMC * 4);
    __hip_bfloat16* h      = (__hip_bfloat16*)alloc((size_t)N * DIMC * 2);
    __hip_bfloat16* qkv    = (__hip_bfloat16*)alloc((size_t)N * QKVC * 2);
    __hip_bfloat16* agg    = (__hip_bfloat16*)alloc((size_t)N * INNERC * 2);
    __hip_bfloat16* u      = (__hip_bfloat16*)alloc((size_t)N * 1024 * 2);
    int*            rowptr = (int*)alloc((size_t)(N + 1) * 4);
    int*            cnt    = (int*)alloc((size_t)N * 4);
    int*            bsum   = (int*)alloc((size_t)64 * 4);
    int*            srcperm= (int*)alloc((size_t)E * 4);
    __hip_bfloat16* wqkvB  = (__hip_bfloat16*)alloc((size_t)4 * QKVC * DIMC * 2);
    float*          bqkvF  = (float*)alloc((size_t)4 * QKVC * 4);
    __hip_bfloat16* woB    = (__hip_bfloat16*)alloc((size_t)4 * DIMC * INNERC * 2);
    __hip_bfloat16* w1B    = (__hip_bfloat16*)alloc((size_t)4 * 1024 * DIMC * 2);
    __hip_bfloat16* w2B    = (__hip_bfloat16*)alloc((size_t)4 * DIMC * 1024 * 2);

    // Weight conversion (per-call, deterministic)
    packqkv_kernel<<<4 * QKVC, 256, 0, stream>>>(wq, wk, wv, bq, bk, bv, wqkvB, bqkvF);
    {
        int n = 4 * DIMC * INNERC;
        f2b_kernel<<<(n / 4 + 255) / 256, 256, 0, stream>>>(wo, woB, n);
        n = 4 * 1024 * DIMC;
        f2b_kernel<<<(n / 4 + 255) / 256, 256, 0, stream>>>(w1, w1B, n);
        f2b_kernel<<<(n / 4 + 255) / 256, 256, 0, stream>>>(w2, w2B, n);
    }

    // CSR build (hierarchical scan)
    int nb = (N + 1023) / 1024;     // 20
    hipMemsetAsync(cnt, 0, (size_t)N * 4, stream);
    count_kernel<<<(E + 255) / 256, 256, 0, stream>>>(dstIdx, cnt, E);
    scanA_kernel<<<nb, 1024, 0, stream>>>(cnt, rowptr, bsum, N);
    scanB_kernel<<<1, 64, 0, stream>>>(bsum, nb);
    scanC_kernel<<<nb, 1024, 0, stream>>>(rowptr, bsum, N);
    hipMemsetAsync(cnt, 0, (size_t)N * 4, stream);
    scatter_kernel<<<(E + 255) / 256, 256, 0, stream>>>(srcIdx, dstIdx, rowptr, cnt, srcperm, E);

    int mt = (N + 127) / 128;        // 157
    int lnBlocks = (N + 3) / 4;      // 5000
    int attnBlocks = (N * 64 + 255) / 256;
    for (int l = 0; l < 4; ++l) {
        const float* xin = (l == 0) ? x : xbuf;
        ln_kernel<<<lnBlocks, 256, 0, stream>>>(xin, ln1g + l * DIMC, ln1b + l * DIMC, h, N);
        // QKV: OUT=384 -> 3 ntiles, 471 blocks
        mfma_gemm<0><<<mt * 3, 512, 0, stream>>>(
            h, wqkvB + (size_t)l * QKVC * DIMC, bqkvF + l * QKVC, nullptr,
            qkv, N, DIMC, QKVC, mt, 3);
        attn_kernel<<<attnBlocks, 256, 0, stream>>>(qkv, rowptr, srcperm, agg, N);
        // out-proj: OUT=256, K=128 -> 314 blocks
        mfma_gemm<2><<<mt * 2, 512, 0, stream>>>(
            agg, woB + (size_t)l * DIMC * INNERC, bo + l * DIMC, xin,
            xbuf, N, INNERC, DIMC, mt, 2);
        ln_kernel<<<lnBlocks, 256, 0, stream>>>(xbuf, ln2g + l * DIMC, ln2b + l * DIMC, h, N);
        // FF1: OUT=1024 -> 8 ntiles, 1256 blocks
        mfma_gemm<1><<<mt * 8, 512, 0, stream>>>(
            h, w1B + (size_t)l * 1024 * DIMC, b1 + l * 1024, nullptr,
            u, N, DIMC, 1024, mt, 8);
        float* xout = (l == 3) ? (float*)d_out : xbuf;
        // FF2: OUT=256, K=1024 -> 314 blocks, 16 K-steps (pipeline fills)
        mfma_gemm<2><<<mt * 2, 512, 0, stream>>>(
            u, w2B + (size_t)l * DIMC * 1024, b2 + l * DIMC, xbuf,
            xout, N, 1024, DIMC, mt, 2);
    }
}